// Round 1
// baseline (1065.851 us; speedup 1.0000x reference)
//
#include <hip/hip_runtime.h>
#include <math.h>

#define BATCH   8192
#define NSTEPS  5000
#define SEG     50
#define NSEG    100          // NSTEPS / SEG
#define NSEG_USED 98         // only steps 0..4899 are ever observed
#define TPB     32           // half-waves: spread HBM traffic over all 256 CUs

__global__ __launch_bounds__(TPB, 1)
void sir_sde_kernel(const float* __restrict__ cond,
                    const float* __restrict__ dW,
                    const float* __restrict__ uu,
                    float* __restrict__ out)
{
    const int b = blockIdx.x * TPB + threadIdx.x;

    const float inf_rate = cond[b * 4 + 0];
    const float rec      = cond[b * 4 + 1];
    const float mr       = cond[b * 4 + 2];
    const float vol      = cond[b * 4 + 3];

    const float dt    = 0.01f;
    const float r0i   = inf_rate / rec;
    const float dtrec = dt * rec;
    const float ci    = 1.0f - dtrec;         // i' = i*ci + ps
    const float c1    = 1.0f - dt * mr;       // r0' = r0*c1 + c2 + sqrt|r0|*g
    const float c2    = (dt * mr) * r0i;
    const float volc  = vol * sqrtf(dt);      // folds at compile time into one const mul

    float s  = 0.99f;
    float i_ = 0.01f;
    float r0 = r0i;

    // streaming stats over the 49 recorded samples
    float maxv = -1.0f, maxat = 0.0f;
    float prevlx = 0.0f, sum = 0.0f, sumsq = 0.0f;
    int   reccount = 0;

    // double-buffered dW segments (registers; occupancy irrelevant at 128-256 waves total)
    float bufA[SEG], bufB[SEG];
    const float* dWb = dW + b;

#pragma unroll
    for (int j = 0; j < SEG; ++j)
        bufA[j] = dWb[(size_t)j * BATCH];

    for (int sg = 0; sg < NSEG_USED; sg += 2) {
        // prefetch odd segment sg+1 -> bufB (in flight while computing bufA)
#pragma unroll
        for (int j = 0; j < SEG; ++j)
            bufB[j] = dWb[(size_t)((sg + 1) * SEG + j) * BATCH];

        // compute even segment sg  (t = sg*50 + j; t%100 = j, never 99 -> no record)
#pragma unroll
        for (int j = 0; j < SEG; ++j) {
            float dw  = bufA[j];
            float p   = dtrec * r0;
            float ps  = p * s;
            float r0a = r0 * c1 + c2;
            float sq  = sqrtf(fabsf(r0));
            float g   = dw * volc;
            s  = s - ps;
            i_ = i_ * ci + ps;
            r0 = r0a + sq * g;
        }

        // prefetch even segment sg+2 -> bufA (clamp OOB to segment 0; values unused)
        const int nsg = (sg + 2 < NSEG_USED) ? (sg + 2) : 0;
#pragma unroll
        for (int j = 0; j < SEG; ++j)
            bufA[j] = dWb[(size_t)(nsg * SEG + j) * BATCH];

        // compute odd segment sg+1 (t%100 == 99 exactly at j == SEG-1)
#pragma unroll
        for (int j = 0; j < SEG; ++j) {
            float dw  = bufB[j];
            float p   = dtrec * r0;
            float ps  = p * s;
            float r0a = r0 * c1 + c2;
            float sq  = sqrtf(fabsf(r0));
            float g   = dw * volc;
            s  = s - ps;
            i_ = i_ * ci + ps;
            r0 = r0a + sq * g;
            if (j == SEG - 1) {
                // record infected after this step: nan_to_num(...)->clip(1e-5)
                float x = __builtin_isfinite(i_) ? i_ : 0.0f;
                x = fmaxf(x, 1e-5f);
                float lx = logf(x);
                if (reccount > 0) {            // uniform branch
                    float d = lx - prevlx;
                    sum   += d;
                    sumsq += d * d;
                }
                prevlx = lx;
                if (x > maxv) { maxv = x; maxat = (float)reccount; } // strict > => first max
                ++reccount;
            }
        }
    }

    // epilogue: std (ddof=0 over 48 diffs), max_at = (argmax + u)/49
    float mean = sum / 48.0f;
    float var  = sumsq / 48.0f - mean * mean;
    var = fmaxf(var, 0.0f);
    float volout    = sqrtf(var);
    float maxat_out = (maxat + uu[b]) / 49.0f;

    out[b * 3 + 0] = maxv;
    out[b * 3 + 1] = maxat_out;
    out[b * 3 + 2] = volout;
}

extern "C" void kernel_launch(void* const* d_in, const int* in_sizes, int n_in,
                              void* d_out, int out_size, void* d_ws, size_t ws_size,
                              hipStream_t stream)
{
    (void)in_sizes; (void)n_in; (void)out_size; (void)d_ws; (void)ws_size;
    const float* cond = (const float*)d_in[0];
    const float* dW   = (const float*)d_in[1];
    const float* uu   = (const float*)d_in[2];
    float* out = (float*)d_out;

    dim3 grid(BATCH / TPB), block(TPB);
    hipLaunchKernelGGL(sir_sde_kernel, grid, block, 0, stream, cond, dW, uu, out);
}

// Round 2
// 642.308 us; speedup vs baseline: 1.6594x; 1.6594x over previous
//
#include <hip/hip_runtime.h>
#include <math.h>

#define BATCH     8192
#define SEG       25
#define NSEG_USED 196      // 196*25 = 4900 steps; steps 4900..4999 never observed
#define TPB       32       // half-waves: 256 blocks -> 1 wave on each of 256 CUs

__global__ __launch_bounds__(TPB, 1)
void sir_sde_kernel(const float* __restrict__ cond,
                    const float* __restrict__ dW,
                    const float* __restrict__ uu,
                    float* __restrict__ out)
{
    const int b = blockIdx.x * TPB + threadIdx.x;

    const float inf_rate = cond[b * 4 + 0];
    const float rec      = cond[b * 4 + 1];
    const float mr       = cond[b * 4 + 2];
    const float vol      = cond[b * 4 + 3];

    const float dt    = 0.01f;
    const float r0i   = inf_rate / rec;
    const float dtrec = dt * rec;
    const float ci    = 1.0f - dtrec;       // i' = i*ci + ps
    const float c1    = 1.0f - dt * mr;     // r0' = r0*c1 + c2 + sqrt|r0|*g
    const float c2    = (dt * mr) * r0i;
    const float volc  = vol * sqrtf(dt);

    float s  = 0.99f;
    float i_ = 0.01f;
    float r0 = r0i;

    // streaming stats over the 49 recorded samples
    float maxv = -1.0f, maxat = 0.0f;
    float prevlx = 0.0f, sum = 0.0f, sumsq = 0.0f;
    int   reccount = 0;

    // register double buffer; sched_barrier(0) walls stop the compiler from
    // sinking the prefetch loads down to their uses (round-1 failure mode:
    // VGPR_Count=80 proved the 50-deep buffers were demoted -> latency-bound)
    float bufA[SEG], bufB[SEG];
    const float* dWb = dW + b;

#pragma unroll
    for (int j = 0; j < SEG; ++j)
        bufA[j] = dWb[(size_t)j * BATCH];

    for (int sg = 0; sg < NSEG_USED; sg += 2) {
        // ---- prefetch segment sg+1 (25 loads in flight over the compute) ----
        __builtin_amdgcn_sched_barrier(0);
#pragma unroll
        for (int j = 0; j < SEG; ++j)
            bufB[j] = dWb[(size_t)((sg + 1) * SEG + j) * BATCH];
        __builtin_amdgcn_sched_barrier(0);

        // ---- compute segment sg (even: sg%4 in {0,2}, never records) ----
#pragma unroll
        for (int j = 0; j < SEG; ++j) {
            float dw  = bufA[j];
            float p   = dtrec * r0;
            float ps  = p * s;
            float r0a = r0 * c1 + c2;
            float sq  = sqrtf(fabsf(r0));
            float g   = dw * volc;
            s  = s - ps;
            i_ = i_ * ci + ps;
            r0 = r0a + sq * g;
        }

        // ---- prefetch segment sg+2 (OOB -> reload seg 0, values unused) ----
        __builtin_amdgcn_sched_barrier(0);
        const int nsg = (sg + 2 < NSEG_USED) ? (sg + 2) : 0;
#pragma unroll
        for (int j = 0; j < SEG; ++j)
            bufA[j] = dWb[(size_t)(nsg * SEG + j) * BATCH];
        __builtin_amdgcn_sched_barrier(0);

        // ---- compute segment sg+1 (records iff (sg+1)%4==3, at j==24) ----
        const bool recseg = ((sg & 3) == 2);   // wave-uniform
#pragma unroll
        for (int j = 0; j < SEG; ++j) {
            float dw  = bufB[j];
            float p   = dtrec * r0;
            float ps  = p * s;
            float r0a = r0 * c1 + c2;
            float sq  = sqrtf(fabsf(r0));
            float g   = dw * volc;
            s  = s - ps;
            i_ = i_ * ci + ps;
            r0 = r0a + sq * g;
            if (j == SEG - 1 && recseg) {
                // record infected after this step: nan_to_num -> clip(1e-5)
                float x = __builtin_isfinite(i_) ? i_ : 0.0f;
                x = fmaxf(x, 1e-5f);
                float lx = logf(x);
                if (reccount > 0) {
                    float d = lx - prevlx;
                    sum   += d;
                    sumsq += d * d;
                }
                prevlx = lx;
                if (x > maxv) { maxv = x; maxat = (float)reccount; } // strict >: first max
                ++reccount;
            }
        }
    }

    // epilogue: std (ddof=0 over 48 diffs), max_at = (argmax + u)/49
    float mean = sum / 48.0f;
    float var  = sumsq / 48.0f - mean * mean;
    var = fmaxf(var, 0.0f);
    float volout    = sqrtf(var);
    float maxat_out = (maxat + uu[b]) / 49.0f;

    out[b * 3 + 0] = maxv;
    out[b * 3 + 1] = maxat_out;
    out[b * 3 + 2] = volout;
}

extern "C" void kernel_launch(void* const* d_in, const int* in_sizes, int n_in,
                              void* d_out, int out_size, void* d_ws, size_t ws_size,
                              hipStream_t stream)
{
    (void)in_sizes; (void)n_in; (void)out_size; (void)d_ws; (void)ws_size;
    const float* cond = (const float*)d_in[0];
    const float* dW   = (const float*)d_in[1];
    const float* uu   = (const float*)d_in[2];
    float* out = (float*)d_out;

    dim3 grid(BATCH / TPB), block(TPB);
    hipLaunchKernelGGL(sir_sde_kernel, grid, block, 0, stream, cond, dW, uu, out);
}

// Round 3
// 625.636 us; speedup vs baseline: 1.7036x; 1.0266x over previous
//
#include <hip/hip_runtime.h>
#include <math.h>

#define BATCH 8192
#define TPB   32      // half-waves: 256 blocks -> 1 wave on each of 256 CUs
#define SEGN  25      // 196 segments * 25 = 4900 steps (steps 4900..4999 unobserved)

// ---- macro machinery: 25 NAMED scalars per buffer (SSA values, cannot be
// demoted to scratch -- round 1/2 failure mode: indexed arrays collapsed to
// VGPR_Count 80/48, loads serialized at ~235 cyc/step) ----
#define REP25(M) M(0) M(1) M(2) M(3) M(4) M(5) M(6) M(7) M(8) M(9) \
  M(10) M(11) M(12) M(13) M(14) M(15) M(16) M(17) M(18) M(19) \
  M(20) M(21) M(22) M(23) M(24)

#define DECL_A(k) float a##k;
#define DECL_B(k) float b##k;
#define LD_A(k)   a##k = pA[(size_t)(k) * BATCH];
#define LD_B(k)   b##k = pB[(size_t)(k) * BATCH];

#define STEP_BODY(dwv) { \
    float dw  = (dwv); \
    float pr  = dtrec * r0; \
    float ps  = pr * s; \
    float r0a = r0 * c1 + c2; \
    float sq  = sqrtf(fabsf(r0)); \
    float g   = dw * volc; \
    s  = s - ps; \
    i_ = i_ * ci + ps; \
    r0 = r0a + sq * g; }

#define STEP_A(k) STEP_BODY(a##k)
#define STEP_B(k) STEP_BODY(b##k)

__global__ __launch_bounds__(TPB, 1)
void sir_sde_kernel(const float* __restrict__ cond,
                    const float* __restrict__ dW,
                    const float* __restrict__ uu,
                    float* __restrict__ out)
{
    const int b = blockIdx.x * TPB + threadIdx.x;

    const float inf_rate = cond[b * 4 + 0];
    const float rec      = cond[b * 4 + 1];
    const float mr       = cond[b * 4 + 2];
    const float vol      = cond[b * 4 + 3];

    const float dt    = 0.01f;
    const float r0i   = inf_rate / rec;
    const float dtrec = dt * rec;
    const float ci    = 1.0f - dtrec;       // i' = i*ci + ps
    const float c1    = 1.0f - dt * mr;     // r0' = r0*c1 + c2 + sqrt|r0|*g
    const float c2    = (dt * mr) * r0i;
    const float volc  = vol * sqrtf(dt);

    float s  = 0.99f;
    float i_ = 0.01f;
    float r0 = r0i;

    // streaming stats over the 49 recorded samples
    float maxv = -1.0f, maxat = 0.0f;
    float prevlx = 0.0f, sum = 0.0f, sumsq = 0.0f;
    int   reccount = 0;

    REP25(DECL_A)
    REP25(DECL_B)

    const float* dWb = dW + b;
    const float* pA  = dWb;           // segment 0
    const float* pB;

    REP25(LD_A)                       // preheader: segment 0 in flight

    for (int sg = 0; sg < 196; sg += 2) {
        // ---- issue segment sg+1 -> b (25 loads in flight over compute A) ----
        pB = dWb + (size_t)(sg + 1) * SEGN * BATCH;
        __builtin_amdgcn_sched_barrier(0);
        REP25(LD_B)
        __builtin_amdgcn_sched_barrier(0);

        // ---- compute segment sg (first a-use waits vmcnt(25), not 0) ----
        REP25(STEP_A)

        // ---- issue segment sg+2 -> a (last iter: dummy reload of seg 0) ----
        pA = dWb + (size_t)((sg + 2 < 196) ? sg + 2 : 0) * SEGN * BATCH;
        __builtin_amdgcn_sched_barrier(0);
        REP25(LD_A)
        __builtin_amdgcn_sched_barrier(0);

        // ---- compute segment sg+1; its last step index is (sg+1)*25+24 ----
        REP25(STEP_B)

        // record when (sg+1)*25+24 ≡ 99 (mod 100)  <=>  sg % 4 == 2
        if ((sg & 3) == 2) {
            // infected after step t: nan_to_num -> clip(1e-5)
            float x = __builtin_isfinite(i_) ? i_ : 0.0f;
            x = fmaxf(x, 1e-5f);
            float lx = logf(x);
            if (reccount > 0) {
                float d = lx - prevlx;
                sum   += d;
                sumsq += d * d;
            }
            prevlx = lx;
            if (x > maxv) { maxv = x; maxat = (float)reccount; } // strict >: first max
            ++reccount;
        }
    }

    // epilogue: std (ddof=0 over 48 diffs), max_at = (argmax + u)/49
    float mean = sum / 48.0f;
    float var  = sumsq / 48.0f - mean * mean;
    var = fmaxf(var, 0.0f);
    float volout    = sqrtf(var);
    float maxat_out = (maxat + uu[b]) / 49.0f;

    out[b * 3 + 0] = maxv;
    out[b * 3 + 1] = maxat_out;
    out[b * 3 + 2] = volout;
}

extern "C" void kernel_launch(void* const* d_in, const int* in_sizes, int n_in,
                              void* d_out, int out_size, void* d_ws, size_t ws_size,
                              hipStream_t stream)
{
    (void)in_sizes; (void)n_in; (void)out_size; (void)d_ws; (void)ws_size;
    const float* cond = (const float*)d_in[0];
    const float* dW   = (const float*)d_in[1];
    const float* uu   = (const float*)d_in[2];
    float* out = (float*)d_out;

    dim3 grid(BATCH / TPB), block(TPB);
    hipLaunchKernelGGL(sir_sde_kernel, grid, block, 0, stream, cond, dW, uu, out);
}

// Round 4
// 557.200 us; speedup vs baseline: 1.9129x; 1.1228x over previous
//
#include <hip/hip_runtime.h>
#include <math.h>

#define BATCH 8192
#define TPB   32      // half-waves: 256 blocks -> 1 wave on each of 256 CUs
#define SEGN  25      // 196 segments * 25 = 4900 steps (steps 4900..4999 unobserved)

// Rounds 1-3 post-mortem: source-level register pipelines (arrays, named
// scalars, sched_barrier) all collapsed to VGPR_Count=48 -- the compiler
// re-pairs each load with its use to shrink live ranges, serializing at one
// ~225cyc L2/L3 load per step. Fix: the 25-deep load batch lives in inline
// asm (opaque: cannot be reordered or live-range-shrunk), with manual
// s_waitcnt vmcnt(25) so we never wait on the in-flight next segment.

#define REP25(M) M(0) M(1) M(2) M(3) M(4) M(5) M(6) M(7) M(8) M(9) \
  M(10) M(11) M(12) M(13) M(14) M(15) M(16) M(17) M(18) M(19) \
  M(20) M(21) M(22) M(23) M(24)

#define DECL_A(k) float A##k = 0.0f;
#define DECL_B(k) float B##k = 0.0f;
#define DECL_O(k) const unsigned o##k = boff + (unsigned)((k) * BATCH * 4);

// 25 loads, split into two asm blocks (13+12) to keep operand counts modest.
// saddr form: final addr = s[base] + voffset (u32). Stride between steps is
// BATCH*4 = 32768 B (doesn't fit the 13-bit inst offset), so each step has
// its own precomputed voffset VGPR.
#define LOADSEG(P, baseptr) do { \
  asm volatile( \
    "global_load_dword %[d0], %[o0], %[sb]\n\t" \
    "global_load_dword %[d1], %[o1], %[sb]\n\t" \
    "global_load_dword %[d2], %[o2], %[sb]\n\t" \
    "global_load_dword %[d3], %[o3], %[sb]\n\t" \
    "global_load_dword %[d4], %[o4], %[sb]\n\t" \
    "global_load_dword %[d5], %[o5], %[sb]\n\t" \
    "global_load_dword %[d6], %[o6], %[sb]\n\t" \
    "global_load_dword %[d7], %[o7], %[sb]\n\t" \
    "global_load_dword %[d8], %[o8], %[sb]\n\t" \
    "global_load_dword %[d9], %[o9], %[sb]\n\t" \
    "global_load_dword %[d10], %[o10], %[sb]\n\t" \
    "global_load_dword %[d11], %[o11], %[sb]\n\t" \
    "global_load_dword %[d12], %[o12], %[sb]" \
    : [d0] "=v"(P##0), [d1] "=v"(P##1), [d2] "=v"(P##2), [d3] "=v"(P##3), \
      [d4] "=v"(P##4), [d5] "=v"(P##5), [d6] "=v"(P##6), [d7] "=v"(P##7), \
      [d8] "=v"(P##8), [d9] "=v"(P##9), [d10] "=v"(P##10), \
      [d11] "=v"(P##11), [d12] "=v"(P##12) \
    : [o0] "v"(o0), [o1] "v"(o1), [o2] "v"(o2), [o3] "v"(o3), \
      [o4] "v"(o4), [o5] "v"(o5), [o6] "v"(o6), [o7] "v"(o7), \
      [o8] "v"(o8), [o9] "v"(o9), [o10] "v"(o10), [o11] "v"(o11), \
      [o12] "v"(o12), [sb] "s"(baseptr)); \
  asm volatile( \
    "global_load_dword %[d13], %[o13], %[sb]\n\t" \
    "global_load_dword %[d14], %[o14], %[sb]\n\t" \
    "global_load_dword %[d15], %[o15], %[sb]\n\t" \
    "global_load_dword %[d16], %[o16], %[sb]\n\t" \
    "global_load_dword %[d17], %[o17], %[sb]\n\t" \
    "global_load_dword %[d18], %[o18], %[sb]\n\t" \
    "global_load_dword %[d19], %[o19], %[sb]\n\t" \
    "global_load_dword %[d20], %[o20], %[sb]\n\t" \
    "global_load_dword %[d21], %[o21], %[sb]\n\t" \
    "global_load_dword %[d22], %[o22], %[sb]\n\t" \
    "global_load_dword %[d23], %[o23], %[sb]\n\t" \
    "global_load_dword %[d24], %[o24], %[sb]" \
    : [d13] "=v"(P##13), [d14] "=v"(P##14), [d15] "=v"(P##15), \
      [d16] "=v"(P##16), [d17] "=v"(P##17), [d18] "=v"(P##18), \
      [d19] "=v"(P##19), [d20] "=v"(P##20), [d21] "=v"(P##21), \
      [d22] "=v"(P##22), [d23] "=v"(P##23), [d24] "=v"(P##24) \
    : [o13] "v"(o13), [o14] "v"(o14), [o15] "v"(o15), [o16] "v"(o16), \
      [o17] "v"(o17), [o18] "v"(o18), [o19] "v"(o19), [o20] "v"(o20), \
      [o21] "v"(o21), [o22] "v"(o22), [o23] "v"(o23), [o24] "v"(o24), \
      [sb] "s"(baseptr)); \
} while (0)

// Wait until only the newest 25 loads (the just-issued other buffer) remain
// outstanding => this buffer's 25 (older) have landed. Tying the values as
// "+v" makes every use data-depend on the wait.
#define WAITSEG(P) \
  asm volatile("s_waitcnt vmcnt(25)" \
    : "+v"(P##0), "+v"(P##1), "+v"(P##2), "+v"(P##3), "+v"(P##4), \
      "+v"(P##5), "+v"(P##6), "+v"(P##7), "+v"(P##8), "+v"(P##9), \
      "+v"(P##10), "+v"(P##11), "+v"(P##12), "+v"(P##13), "+v"(P##14), \
      "+v"(P##15), "+v"(P##16), "+v"(P##17), "+v"(P##18), "+v"(P##19), \
      "+v"(P##20), "+v"(P##21), "+v"(P##22), "+v"(P##23), "+v"(P##24))

#define STEP_BODY(dwv) { \
    float dw  = (dwv); \
    float pr  = dtrec * r0; \
    float ps  = pr * s; \
    float r0a = r0 * c1 + c2; \
    float sq  = sqrtf(fabsf(r0)); \
    float g   = dw * volc; \
    s  = s - ps; \
    i_ = i_ * ci + ps; \
    r0 = r0a + sq * g; }

#define STEP_A(k) STEP_BODY(A##k)
#define STEP_B(k) STEP_BODY(B##k)

__global__ __launch_bounds__(TPB, 1)
void sir_sde_kernel(const float* __restrict__ cond,
                    const float* __restrict__ dW,
                    const float* __restrict__ uu,
                    float* __restrict__ out)
{
    const int b = blockIdx.x * TPB + threadIdx.x;

    const float inf_rate = cond[b * 4 + 0];
    const float rec      = cond[b * 4 + 1];
    const float mr       = cond[b * 4 + 2];
    const float vol      = cond[b * 4 + 3];

    const float dt    = 0.01f;
    const float r0i   = inf_rate / rec;
    const float dtrec = dt * rec;
    const float ci    = 1.0f - dtrec;       // i' = i*ci + ps
    const float c1    = 1.0f - dt * mr;     // r0' = r0*c1 + c2 + sqrt|r0|*g
    const float c2    = (dt * mr) * r0i;
    const float volc  = vol * sqrtf(dt);

    float s  = 0.99f;
    float i_ = 0.01f;
    float r0 = r0i;

    // streaming stats over the 49 recorded samples
    float maxv = -1.0f, maxat = 0.0f;
    float prevlx = 0.0f, sum = 0.0f, sumsq = 0.0f;
    int   reccount = 0;

    REP25(DECL_A)
    REP25(DECL_B)

    const unsigned boff = (unsigned)b * 4u;     // per-lane byte offset (divergent, VGPR)
    REP25(DECL_O)                               // o_k = b*4 + k*32768, all < 2^20

    // preheader: segment 0 in flight
    LOADSEG(A, dW);

    for (int sg = 0; sg < 196; sg += 2) {
        // issue segment sg+1 (base is wave-uniform -> SGPR pair)
        const float* bB = dW + (size_t)(sg + 1) * (SEGN * BATCH);
        LOADSEG(B, bB);

        // wait only for segment sg's 25 (older); sg+1's stay in flight
        WAITSEG(A);
        REP25(STEP_A)

        // issue segment sg+2 (last iter: dummy reload of seg 0, never waited
        // per-value; drained by the trailing vmcnt(0))
        const float* bA = dW + (size_t)((sg + 2 < 196) ? sg + 2 : 0) * (SEGN * BATCH);
        LOADSEG(A, bA);

        WAITSEG(B);
        REP25(STEP_B)

        // segment sg+1 ends at step (sg+1)*25+24; ==99 (mod 100) iff sg%4==2
        if ((sg & 3) == 2) {
            // infected after this step: nan_to_num -> clip(1e-5)
            float x = __builtin_isfinite(i_) ? i_ : 0.0f;
            x = fmaxf(x, 1e-5f);
            float lx = logf(x);
            if (reccount > 0) {
                float d = lx - prevlx;
                sum   += d;
                sumsq += d * d;
            }
            prevlx = lx;
            if (x > maxv) { maxv = x; maxat = (float)reccount; } // strict >: first max
            ++reccount;
        }
    }

    // drain the final dummy batch before the wave can touch memory/exit
    asm volatile("s_waitcnt vmcnt(0)" ::: "memory");

    // epilogue: std (ddof=0 over 48 diffs), max_at = (argmax + u)/49
    float mean = sum / 48.0f;
    float var  = sumsq / 48.0f - mean * mean;
    var = fmaxf(var, 0.0f);
    float volout    = sqrtf(var);
    float maxat_out = (maxat + uu[b]) / 49.0f;

    out[b * 3 + 0] = maxv;
    out[b * 3 + 1] = maxat_out;
    out[b * 3 + 2] = volout;
}

extern "C" void kernel_launch(void* const* d_in, const int* in_sizes, int n_in,
                              void* d_out, int out_size, void* d_ws, size_t ws_size,
                              hipStream_t stream)
{
    (void)in_sizes; (void)n_in; (void)out_size; (void)d_ws; (void)ws_size;
    const float* cond = (const float*)d_in[0];
    const float* dW   = (const float*)d_in[1];
    const float* uu   = (const float*)d_in[2];
    float* out = (float*)d_out;

    dim3 grid(BATCH / TPB), block(TPB);
    hipLaunchKernelGGL(sir_sde_kernel, grid, block, 0, stream, cond, dW, uu, out);
}